// Round 5
// baseline (375.220 us; speedup 1.0000x reference)
//
#include <hip/hip_runtime.h>
#include <hip/hip_bf16.h>

#define N_NODES 100000
#define N_EDGES 1600000
#define IN_CH 50
#define EPB 4096
#define NBLK_A ((N_EDGES + EPB - 1) / EPB)        // 391 edge blocks
#define PAD_BLOCKS ((N_NODES * 64) / 1024)        // 6250 pad blocks (1024 thr)

// ---- 1. count degrees via global atomics (cnt is 400KB -> L2-resident)
//      + extra blocks: pad x -> xb bf16 (64ch, zero-padded) ----
__global__ __launch_bounds__(1024) void count_pad(
    const int* __restrict__ dst, int* __restrict__ cnt,
    const float* __restrict__ x, unsigned short* __restrict__ xb) {
    if (blockIdx.x >= NBLK_A) {                    // pad lane
        int t = (blockIdx.x - NBLK_A) * 1024 + threadIdx.x;  // < N_NODES*64
        int n = t >> 6, c = t & 63;
        float v = (c < IN_CH) ? x[n * IN_CH + c] : 0.0f;
        __hip_bfloat16 hb = __float2bfloat16(v);
        xb[t] = *(unsigned short*)&hb;
        return;
    }
    int e0 = blockIdx.x * EPB;
    int e1 = min(e0 + EPB, N_EDGES);
    for (int i = e0 + threadIdx.x; i < e1; i += 1024)
        atomicAdd(&cnt[dst[i]], 1);
}

// ---- 2. allocate contiguous CSR rows: wave-scan of cnt + one atomic per wave.
//      Rows are contiguous per node but NOT globally ordered -- gather doesn't care.
__global__ __launch_bounds__(256) void alloc_rows(
    const int* __restrict__ cnt, int* __restrict__ row_start,
    int* __restrict__ gcur) {
    int n = blockIdx.x * 256 + threadIdx.x;
    int lane = threadIdx.x & 63;
    int v = (n < N_NODES) ? cnt[n] : 0;
    int s = v;                                     // wave inclusive scan
    #pragma unroll
    for (int off = 1; off < 64; off <<= 1) {
        int t = __shfl_up(s, off);
        if (lane >= off) s += t;
    }
    int total = __shfl(s, 63);
    int base = 0;
    if (lane == 63) base = atomicAdd(gcur, total);
    base = __shfl(base, 63);
    if (n < N_NODES) row_start[n] = base + s - v;
}

// ---- 3. scatter edges into CSR (cursor is 400KB -> L2-resident atomics) ----
__global__ __launch_bounds__(1024) void scatter_csr(
    const int* __restrict__ src, const int* __restrict__ dst,
    const int* __restrict__ row_start, int* __restrict__ cur,
    int* __restrict__ csr_src) {
    int e0 = blockIdx.x * EPB;
    int e1 = min(e0 + EPB, N_EDGES);
    for (int i = e0 + threadIdx.x; i < e1; i += 1024) {
        int d = dst[i];
        int k = atomicAdd(&cur[d], 1);
        csr_src[row_start[d] + k] = src[i];
    }
}

// unpack 8 bf16 from uint4, predicated fma into acc[0..8)
__device__ __forceinline__ void upadd8(float* a, uint4 v, float p) {
    a[0] = fmaf(p, __uint_as_float(v.x << 16), a[0]);
    a[1] = fmaf(p, __uint_as_float(v.x & 0xffff0000u), a[1]);
    a[2] = fmaf(p, __uint_as_float(v.y << 16), a[2]);
    a[3] = fmaf(p, __uint_as_float(v.y & 0xffff0000u), a[3]);
    a[4] = fmaf(p, __uint_as_float(v.z << 16), a[4]);
    a[5] = fmaf(p, __uint_as_float(v.z & 0xffff0000u), a[5]);
    a[6] = fmaf(p, __uint_as_float(v.w << 16), a[6]);
    a[7] = fmaf(p, __uint_as_float(v.w & 0xffff0000u), a[7]);
}

// wave-local LDS fence: LDS ops of one wave complete in order; no block barrier.
#define WAVE_LDS_FENCE() __asm__ volatile("s_waitcnt lgkmcnt(0)" ::: "memory")

// Gather-mean of 2 nodes per wave over 64-ch bf16 rows (R2-proven shape).
__device__ __forceinline__ void gather2(
    const unsigned short* __restrict__ featb, const int* __restrict__ csr_src,
    const int* __restrict__ row_start, const int* __restrict__ cnt,
    int nb, int lane, float acc[2][8]) {
    int g  = lane >> 3;
    int cw = (lane & 7) * 8;
    int start[2], deg[2], sv[2];
    #pragma unroll
    for (int i = 0; i < 2; ++i) {
        start[i] = row_start[nb + i];
        deg[i]   = cnt[nb + i];
        #pragma unroll
        for (int c = 0; c < 8; ++c) acc[i][c] = 0.f;
    }
    int dmax = max(deg[0], deg[1]);
    #pragma unroll
    for (int i = 0; i < 2; ++i)
        sv[i] = (lane < deg[i]) ? csr_src[start[i] + lane] : 0;

    #pragma unroll
    for (int cb = 0; cb < 64; cb += 16) {
        if (cb >= dmax) break;                 // wave-uniform
        int s00 = __shfl(sv[0], cb + g);
        int s01 = __shfl(sv[0], cb + 8 + g);
        int s10 = __shfl(sv[1], cb + g);
        int s11 = __shfl(sv[1], cb + 8 + g);
        uint4 v00 = *(const uint4*)(featb + s00 * 64 + cw);
        uint4 v01 = *(const uint4*)(featb + s01 * 64 + cw);
        uint4 v10 = *(const uint4*)(featb + s10 * 64 + cw);
        uint4 v11 = *(const uint4*)(featb + s11 * 64 + cw);
        int rem0 = deg[0] - cb;
        int rem1 = deg[1] - cb;
        upadd8(acc[0], v00, (g < rem0) ? 1.f : 0.f);
        upadd8(acc[0], v01, (g + 8 < rem0) ? 1.f : 0.f);
        upadd8(acc[1], v10, (g < rem1) ? 1.f : 0.f);
        upadd8(acc[1], v11, (g + 8 < rem1) ? 1.f : 0.f);
    }
    if (dmax > 64) {                           // rare tail (Poisson(16): ~never)
        for (int i = 0; i < 2; ++i) {
            for (int c0 = 64; c0 < deg[i]; c0 += 64) {
                int rem = deg[i] - c0; if (rem > 64) rem = 64;
                int sx = (lane < rem) ? csr_src[start[i] + c0 + lane] : 0;
                for (int cb = 0; cb < rem; cb += 16) {
                    int s0 = __shfl(sx, cb + g);
                    int s1 = __shfl(sx, cb + 8 + g);
                    float p0 = (cb + g < rem) ? 1.f : 0.f;
                    float p1 = (cb + 8 + g < rem) ? 1.f : 0.f;
                    uint4 v0 = *(const uint4*)(featb + s0 * 64 + cw);
                    uint4 v1 = *(const uint4*)(featb + s1 * 64 + cw);
                    upadd8(acc[i], v0, p0);
                    upadd8(acc[i], v1, p1);
                }
            }
        }
    }
    #pragma unroll
    for (int i = 0; i < 2; ++i) {
        float inv = 1.0f / fmaxf((float)deg[i], 1.0f);
        #pragma unroll
        for (int c = 0; c < 8; ++c) {
            float t = acc[i][c];
            t += __shfl_xor(t, 8);
            t += __shfl_xor(t, 16);
            t += __shfl_xor(t, 32);
            acc[i][c] = t * inv;
        }
    }
}

__device__ __forceinline__ float bf16u(unsigned short u) {
    return __uint_as_float(((unsigned)u) << 16);
}

// ---- 4. layer 1 (R2/R4-proven): 2 nodes/wave; gather(xb) + W1 GEMM -> h1b ----
__global__ __launch_bounds__(256, 8) void layer1_fused(
    const unsigned short* __restrict__ xb,
    const int* __restrict__ csr_src, const int* __restrict__ row_start,
    const int* __restrict__ cnt, const float* __restrict__ W1,
    const float* __restrict__ b1, unsigned short* __restrict__ h1b) {
    int wv   = threadIdx.x >> 6;
    int lane = threadIdx.x & 63;
    int nb   = (blockIdx.x * 4 + wv) * 2;      // N_NODES % 8 == 0

    float acc[2][8];
    gather2(xb, csr_src, row_start, cnt, nb, lane, acc);

    __shared__ __align__(16) float selfF[4][2][64];
    __shared__ __align__(16) float meanF[4][2][64];
    #pragma unroll
    for (int i = 0; i < 2; ++i) {
        selfF[wv][i][lane] = bf16u(xb[((nb + i) << 6) + lane]);
        if (lane < 8) {
            *(float4*)&meanF[wv][i][lane * 8] =
                make_float4(acc[i][0], acc[i][1], acc[i][2], acc[i][3]);
            *(float4*)&meanF[wv][i][lane * 8 + 4] =
                make_float4(acc[i][4], acc[i][5], acc[i][6], acc[i][7]);
        }
    }
    WAVE_LDS_FENCE();

    float ao[2];
    float bb = b1[lane];
    #pragma unroll
    for (int i = 0; i < 2; ++i) ao[i] = bb;
    #pragma unroll
    for (int k = 0; k < IN_CH; ++k) {
        float w = W1[k * 64 + lane];           // lanes coalesced, reused x2
        #pragma unroll
        for (int i = 0; i < 2; ++i) ao[i] = fmaf(selfF[wv][i][k], w, ao[i]);
    }
    #pragma unroll
    for (int k = 0; k < IN_CH; ++k) {
        float w = W1[(IN_CH + k) * 64 + lane];
        #pragma unroll
        for (int i = 0; i < 2; ++i) ao[i] = fmaf(meanF[wv][i][k], w, ao[i]);
    }
    #pragma unroll
    for (int i = 0; i < 2; ++i) {
        float r = fmaxf(ao[i], 0.f);
        __hip_bfloat16 hb = __float2bfloat16(r);
        h1b[((nb + i) << 6) + lane] = *(unsigned short*)&hb;
    }
}

// ---- 4b. W2 pre-transform v2 (R5): 4 nodes/wave, all 64 lanes active.
//      lane<32: ys ch j (self, fp32); lane>=32: ym ch j (mean side, bf16 out).
//      h-rows staged in LDS once (free broadcasts); W2 from global (16KB, L1-hot).
__global__ __launch_bounds__(256) void transform_w2(
    const unsigned short* __restrict__ h1b,
    const float* __restrict__ W2, const float* __restrict__ b2,
    unsigned short* __restrict__ y2b, float* __restrict__ yselff) {
    __shared__ __align__(16) float hrowF[4][4][64];    // 16KB: [wave][node][ch]
    int t    = threadIdx.x;
    int wv   = t >> 6;
    int lane = t & 63;
    int nb4  = blockIdx.x * 16 + wv * 4;               // grid*16 == N_NODES

    // stage 4 rows: lane l -> node l>>4, dword-pair (l&15) = channels 4q..4q+3
    {
        int in = lane >> 4, q = lane & 15;
        uint2 hv = *(const uint2*)(h1b + (nb4 + in) * 64 + q * 4);
        float4 f;
        f.x = __uint_as_float(hv.x << 16);
        f.y = __uint_as_float(hv.x & 0xffff0000u);
        f.z = __uint_as_float(hv.y << 16);
        f.w = __uint_as_float(hv.y & 0xffff0000u);
        *(float4*)&hrowF[wv][in][q * 4] = f;
    }
    WAVE_LDS_FENCE();

    int jj  = lane & 31;
    int sel = lane >> 5;                               // 0: self (ys), 1: mean (ym)
    const float* Wp = W2 + sel * 64 * 32 + jj;
    float a[4] = {0.f, 0.f, 0.f, 0.f};
    #pragma unroll
    for (int k = 0; k < 64; ++k) {
        float w = Wp[k * 32];                          // 2 coalesced rows / wave
        #pragma unroll
        for (int i = 0; i < 4; ++i)
            a[i] = fmaf(hrowF[wv][i][k], w, a[i]);     // LDS broadcast
    }
    if (sel == 0) {
        float bb = b2[jj];
        #pragma unroll
        for (int i = 0; i < 4; ++i)
            yselff[(nb4 + i) * 32 + jj] = a[i] + bb;
    } else {
        #pragma unroll
        for (int i = 0; i < 4; ++i) {
            __hip_bfloat16 hb = __float2bfloat16(a[i]);
            y2b[(nb4 + i) * 32 + jj] = *(unsigned short*)&hb;
        }
    }
}

// ---- 5. layers 2+3 (R3/R4-proven slim): gather y2b (32ch bf16, 64B/edge,
//      32 neighbors per round trip), mean, add yself, ReLU, dot W3.
__global__ __launch_bounds__(256, 8) void layer23_fused(
    const unsigned short* __restrict__ y2b,
    const int* __restrict__ csr_src, const int* __restrict__ row_start,
    const int* __restrict__ cnt, const float* __restrict__ yselff,
    const float* __restrict__ W3, const float* __restrict__ b3,
    float* __restrict__ out) {
    int wv   = threadIdx.x >> 6;
    int lane = threadIdx.x & 63;
    int nb   = (blockIdx.x * 4 + wv) * 2;
    int g  = lane >> 2;                        // 16 groups of 4 lanes
    int cw = (lane & 3) * 8;                   // bf16 offset within 32-ch row

    int start[2], deg[2], sv[2];
    float acc[2][8];
    #pragma unroll
    for (int i = 0; i < 2; ++i) {
        start[i] = row_start[nb + i];
        deg[i]   = cnt[nb + i];
        #pragma unroll
        for (int c = 0; c < 8; ++c) acc[i][c] = 0.f;
    }
    int dmax = max(deg[0], deg[1]);
    #pragma unroll
    for (int i = 0; i < 2; ++i)
        sv[i] = (lane < deg[i]) ? csr_src[start[i] + lane] : 0;

    #pragma unroll
    for (int cb = 0; cb < 64; cb += 32) {      // 32 neighbors per round trip
        if (cb >= dmax) break;                 // wave-uniform
        int s00 = __shfl(sv[0], cb + g);
        int s01 = __shfl(sv[0], cb + 16 + g);
        int s10 = __shfl(sv[1], cb + g);
        int s11 = __shfl(sv[1], cb + 16 + g);
        uint4 v00 = *(const uint4*)(y2b + s00 * 32 + cw);
        uint4 v01 = *(const uint4*)(y2b + s01 * 32 + cw);
        uint4 v10 = *(const uint4*)(y2b + s10 * 32 + cw);
        uint4 v11 = *(const uint4*)(y2b + s11 * 32 + cw);
        int rem0 = deg[0] - cb;
        int rem1 = deg[1] - cb;
        upadd8(acc[0], v00, (g < rem0) ? 1.f : 0.f);
        upadd8(acc[0], v01, (g + 16 < rem0) ? 1.f : 0.f);
        upadd8(acc[1], v10, (g < rem1) ? 1.f : 0.f);
        upadd8(acc[1], v11, (g + 16 < rem1) ? 1.f : 0.f);
    }
    if (dmax > 64) {                           // rare tail
        for (int i = 0; i < 2; ++i) {
            for (int c0 = 64; c0 < deg[i]; c0 += 64) {
                int rem = deg[i] - c0; if (rem > 64) rem = 64;
                int sx = (lane < rem) ? csr_src[start[i] + c0 + lane] : 0;
                for (int cb = 0; cb < rem; cb += 32) {
                    int s0 = __shfl(sx, cb + g);
                    int s1 = __shfl(sx, cb + 16 + g);
                    float p0 = (cb + g < rem) ? 1.f : 0.f;
                    float p1 = (cb + 16 + g < rem) ? 1.f : 0.f;
                    uint4 v0 = *(const uint4*)(y2b + s0 * 32 + cw);
                    uint4 v1 = *(const uint4*)(y2b + s1 * 32 + cw);
                    upadd8(acc[i], v0, p0);
                    upadd8(acc[i], v1, p1);
                }
            }
        }
    }

    // reduce across the 16 groups (lane bits 2..5), apply mean
    __shared__ __align__(16) float aggF[4][2][32];
    #pragma unroll
    for (int i = 0; i < 2; ++i) {
        float inv = 1.0f / fmaxf((float)deg[i], 1.0f);
        #pragma unroll
        for (int c = 0; c < 8; ++c) {
            float t = acc[i][c];
            t += __shfl_xor(t, 4);
            t += __shfl_xor(t, 8);
            t += __shfl_xor(t, 16);
            t += __shfl_xor(t, 32);
            acc[i][c] = t * inv;
        }
    }
    if (lane < 4) {
        #pragma unroll
        for (int i = 0; i < 2; ++i) {
            *(float4*)&aggF[wv][i][lane * 8] =
                make_float4(acc[i][0], acc[i][1], acc[i][2], acc[i][3]);
            *(float4*)&aggF[wv][i][lane * 8 + 4] =
                make_float4(acc[i][4], acc[i][5], acc[i][6], acc[i][7]);
        }
    }
    WAVE_LDS_FENCE();

    int hh = lane >> 5;                        // half-wave id: node nb+hh
    int j  = lane & 31;
    float pre = yselff[(nb + hh) * 32 + j] + aggF[wv][hh][j];
    float v0 = fmaxf(pre, 0.f) * W3[j];
    #pragma unroll
    for (int off = 1; off <= 16; off <<= 1)
        v0 += __shfl_xor(v0, off);
    if (j == 0)
        out[nb + hh] = v0 + b3[0];
}

extern "C" void kernel_launch(void* const* d_in, const int* in_sizes, int n_in,
                              void* d_out, int out_size, void* d_ws, size_t ws_size,
                              hipStream_t stream) {
    const float* x   = (const float*)d_in[0];
    const int*   ei  = (const int*)d_in[1];
    const int*   src = ei;
    const int*   dst = ei + N_EDGES;
    const float* W1  = (const float*)d_in[2];
    const float* b1  = (const float*)d_in[3];
    const float* W2  = (const float*)d_in[4];
    const float* b2  = (const float*)d_in[5];
    const float* W3  = (const float*)d_in[6];
    const float* b3  = (const float*)d_in[7];
    float* out = (float*)d_out;

    // ws (~53 MB): gcur[512] | cnt | row_start | cur | csr_src 6.4MB |
    //   xb bf16 12.8MB | h1b bf16 12.8MB | y2b bf16 6.4MB | yselff fp32 12.8MB
    char* ws = (char*)d_ws;
    auto align = [](size_t v) { return (v + 255) & ~(size_t)255; };
    size_t o = 0;
    int* gcur      = (int*)(ws + o); o = align(o + 512 * 4);
    int* cnt       = (int*)(ws + o); o = align(o + (size_t)N_NODES * 4);
    int* row_start = (int*)(ws + o); o = align(o + (size_t)N_NODES * 4);
    int* cur       = (int*)(ws + o); o = align(o + (size_t)N_NODES * 4);
    int* csr_src   = (int*)(ws + o); o = align(o + (size_t)N_EDGES * 4);
    unsigned short* xb  = (unsigned short*)(ws + o); o = align(o + (size_t)N_NODES * 64 * 2);
    unsigned short* h1b = (unsigned short*)(ws + o); o = align(o + (size_t)N_NODES * 64 * 2);
    unsigned short* y2b = (unsigned short*)(ws + o); o = align(o + (size_t)N_NODES * 32 * 2);
    float* yselff = (float*)(ws + o); o = align(o + (size_t)N_NODES * 32 * 4);

    (void)hipMemsetAsync(gcur, 0, 512 * sizeof(int), stream);
    (void)hipMemsetAsync(cnt, 0, (size_t)N_NODES * sizeof(int), stream);
    (void)hipMemsetAsync(cur, 0, (size_t)N_NODES * sizeof(int), stream);

    count_pad<<<NBLK_A + PAD_BLOCKS, 1024, 0, stream>>>(dst, cnt, x, xb);
    alloc_rows<<<(N_NODES + 255) / 256, 256, 0, stream>>>(cnt, row_start, gcur);
    scatter_csr<<<NBLK_A, 1024, 0, stream>>>(src, dst, row_start, cur, csr_src);

    layer1_fused<<<N_NODES / 8, 256, 0, stream>>>(xb, csr_src, row_start, cnt,
                                                  W1, b1, h1b);
    transform_w2<<<N_NODES / 16, 256, 0, stream>>>(h1b, W2, b2, y2b, yselff);
    layer23_fused<<<N_NODES / 8, 256, 0, stream>>>(y2b, csr_src, row_start, cnt,
                                                   yselff, W3, b3, out);
}

// Round 6
// 238.429 us; speedup vs baseline: 1.5737x; 1.5737x over previous
//
#include <hip/hip_runtime.h>
#include <hip/hip_bf16.h>

#define N_NODES 100000
#define N_EDGES 1600000
#define IN_CH 50
#define NPB 256                                   // nodes per bucket (dst >> 8)
#define NB ((N_NODES + NPB - 1) / NPB)            // 391 buckets
#define CAPLOG 13                                 // 8192 slots/bucket (max ~4.4K used)
#define EPB 4096
#define NBLK_A ((N_EDGES + EPB - 1) / EPB)        // 391 bin blocks
#define PAD_BLOCKS ((N_NODES * 64) / 1024)        // 6250 pad blocks (1024 thr)

// ---- 1. bin edges into fixed-capacity buckets (+ extra blocks: pad x->xb bf16) ----
// cursor_rel[b] is RELATIVE (starts 0 via memset); slot = (b<<CAPLOG) + rel.
// Writes to binned stay within 32KB bucket regions, per-block contiguous runs
// (R5 lesson: fully-random 4B CSR writes cost 102MB of write-allocate at HBM).
__global__ __launch_bounds__(1024) void bin_pad_kernel(
    const int* __restrict__ src, const int* __restrict__ dst,
    int* __restrict__ cursor_rel, unsigned* __restrict__ binned,
    const float* __restrict__ x, unsigned short* __restrict__ xb) {
    if (blockIdx.x >= NBLK_A) {                    // pad lane
        int t = (blockIdx.x - NBLK_A) * 1024 + threadIdx.x;  // < N_NODES*64
        int n = t >> 6, c = t & 63;
        float v = (c < IN_CH) ? x[n * IN_CH + c] : 0.0f;
        __hip_bfloat16 hb = __float2bfloat16(v);
        xb[t] = *(unsigned short*)&hb;
        return;
    }
    __shared__ int bc[NB];
    __shared__ int boff[NB];
    int t = threadIdx.x;
    if (t < NB) bc[t] = 0;
    __syncthreads();
    int e0 = blockIdx.x * EPB;
    int e1 = min(e0 + EPB, N_EDGES);
    for (int i = e0 + t; i < e1; i += 1024)
        atomicAdd(&bc[dst[i] >> 8], 1);
    __syncthreads();
    if (t < NB) {
        int v = bc[t];
        int rel = v ? atomicAdd(&cursor_rel[t], v) : 0;
        boff[t] = (t << CAPLOG) + rel;
        bc[t] = 0;                                 // reuse as local cursor
    }
    __syncthreads();
    for (int i = e0 + t; i < e1; i += 1024) {
        int d = dst[i];
        int b = d >> 8;
        int k = atomicAdd(&bc[b], 1);
        binned[boff[b] + k] = ((unsigned)(d & 255) << 17) | (unsigned)src[i];
    }
}

// ---- 2. per-bucket fine sort (u32 payload) -> cnt, row_start, csr_src ----
__global__ __launch_bounds__(1024) void bucket_fine(
    const unsigned* __restrict__ binned, const int* __restrict__ cursor_rel,
    int* __restrict__ cnt, int* __restrict__ row_start, int* __restrict__ csr_src) {
    __shared__ int lcnt[NPB];
    __shared__ int lofs[NPB];
    __shared__ int sc[NPB];
    int t = threadIdx.x;
    int b = blockIdx.x;
    int nbase = b * NPB;
    int bbase = b << CAPLOG;
    int ecnt  = cursor_rel[b];
    if (t < NPB) lcnt[t] = 0;
    __syncthreads();
    for (int i = t; i < ecnt; i += 1024)
        atomicAdd(&lcnt[(binned[bbase + i] >> 17) & 255], 1);
    __syncthreads();
    int v = (t < NPB) ? lcnt[t] : 0;
    if (t < NPB) sc[t] = v;
    __syncthreads();
    for (int off = 1; off < NPB; off <<= 1) {      // Hillis-Steele over 256
        int tmp = (t < NPB && t >= off) ? sc[t - off] : 0;
        __syncthreads();
        if (t < NPB) sc[t] += tmp;
        __syncthreads();
    }
    if (t < NPB) {
        int excl = sc[t] - v;
        lofs[t] = excl;
        int n = nbase + t;
        if (n < N_NODES) { cnt[n] = v; row_start[n] = bbase + excl; }
    }
    __syncthreads();
    for (int i = t; i < ecnt; i += 1024) {
        unsigned p = binned[bbase + i];
        int d = (int)((p >> 17) & 255);
        int k = atomicAdd(&lofs[d], 1);
        csr_src[bbase + k] = (int)(p & 0x1FFFFu);
    }
}

// unpack 8 bf16 from uint4, predicated fma into acc[0..8)
__device__ __forceinline__ void upadd8(float* a, uint4 v, float p) {
    a[0] = fmaf(p, __uint_as_float(v.x << 16), a[0]);
    a[1] = fmaf(p, __uint_as_float(v.x & 0xffff0000u), a[1]);
    a[2] = fmaf(p, __uint_as_float(v.y << 16), a[2]);
    a[3] = fmaf(p, __uint_as_float(v.y & 0xffff0000u), a[3]);
    a[4] = fmaf(p, __uint_as_float(v.z << 16), a[4]);
    a[5] = fmaf(p, __uint_as_float(v.z & 0xffff0000u), a[5]);
    a[6] = fmaf(p, __uint_as_float(v.w << 16), a[6]);
    a[7] = fmaf(p, __uint_as_float(v.w & 0xffff0000u), a[7]);
}

// wave-local LDS fence: LDS ops of one wave complete in order; no block barrier.
#define WAVE_LDS_FENCE() __asm__ volatile("s_waitcnt lgkmcnt(0)" ::: "memory")

// Gather-mean of 2 nodes per wave over 64-ch bf16 rows (R2-proven shape).
__device__ __forceinline__ void gather2(
    const unsigned short* __restrict__ featb, const int* __restrict__ csr_src,
    const int* __restrict__ row_start, const int* __restrict__ cnt,
    int nb, int lane, float acc[2][8]) {
    int g  = lane >> 3;
    int cw = (lane & 7) * 8;
    int start[2], deg[2], sv[2];
    #pragma unroll
    for (int i = 0; i < 2; ++i) {
        start[i] = row_start[nb + i];
        deg[i]   = cnt[nb + i];
        #pragma unroll
        for (int c = 0; c < 8; ++c) acc[i][c] = 0.f;
    }
    int dmax = max(deg[0], deg[1]);
    #pragma unroll
    for (int i = 0; i < 2; ++i)
        sv[i] = (lane < deg[i]) ? csr_src[start[i] + lane] : 0;

    #pragma unroll
    for (int cb = 0; cb < 64; cb += 16) {
        if (cb >= dmax) break;                 // wave-uniform
        int s00 = __shfl(sv[0], cb + g);
        int s01 = __shfl(sv[0], cb + 8 + g);
        int s10 = __shfl(sv[1], cb + g);
        int s11 = __shfl(sv[1], cb + 8 + g);
        uint4 v00 = *(const uint4*)(featb + s00 * 64 + cw);
        uint4 v01 = *(const uint4*)(featb + s01 * 64 + cw);
        uint4 v10 = *(const uint4*)(featb + s10 * 64 + cw);
        uint4 v11 = *(const uint4*)(featb + s11 * 64 + cw);
        int rem0 = deg[0] - cb;
        int rem1 = deg[1] - cb;
        upadd8(acc[0], v00, (g < rem0) ? 1.f : 0.f);
        upadd8(acc[0], v01, (g + 8 < rem0) ? 1.f : 0.f);
        upadd8(acc[1], v10, (g < rem1) ? 1.f : 0.f);
        upadd8(acc[1], v11, (g + 8 < rem1) ? 1.f : 0.f);
    }
    if (dmax > 64) {                           // rare tail (Poisson(16): ~never)
        for (int i = 0; i < 2; ++i) {
            for (int c0 = 64; c0 < deg[i]; c0 += 64) {
                int rem = deg[i] - c0; if (rem > 64) rem = 64;
                int sx = (lane < rem) ? csr_src[start[i] + c0 + lane] : 0;
                for (int cb = 0; cb < rem; cb += 16) {
                    int s0 = __shfl(sx, cb + g);
                    int s1 = __shfl(sx, cb + 8 + g);
                    float p0 = (cb + g < rem) ? 1.f : 0.f;
                    float p1 = (cb + 8 + g < rem) ? 1.f : 0.f;
                    uint4 v0 = *(const uint4*)(featb + s0 * 64 + cw);
                    uint4 v1 = *(const uint4*)(featb + s1 * 64 + cw);
                    upadd8(acc[i], v0, p0);
                    upadd8(acc[i], v1, p1);
                }
            }
        }
    }
    #pragma unroll
    for (int i = 0; i < 2; ++i) {
        float inv = 1.0f / fmaxf((float)deg[i], 1.0f);
        #pragma unroll
        for (int c = 0; c < 8; ++c) {
            float t = acc[i][c];
            t += __shfl_xor(t, 8);
            t += __shfl_xor(t, 16);
            t += __shfl_xor(t, 32);
            acc[i][c] = t * inv;
        }
    }
}

__device__ __forceinline__ float bf16u(unsigned short u) {
    return __uint_as_float(((unsigned)u) << 16);
}

// ---- 3. layer 1 (R2/R4-proven): 2 nodes/wave; gather(xb) + W1 GEMM -> h1b ----
__global__ __launch_bounds__(256, 8) void layer1_fused(
    const unsigned short* __restrict__ xb,
    const int* __restrict__ csr_src, const int* __restrict__ row_start,
    const int* __restrict__ cnt, const float* __restrict__ W1,
    const float* __restrict__ b1, unsigned short* __restrict__ h1b) {
    int wv   = threadIdx.x >> 6;
    int lane = threadIdx.x & 63;
    int nb   = (blockIdx.x * 4 + wv) * 2;      // N_NODES % 8 == 0

    float acc[2][8];
    gather2(xb, csr_src, row_start, cnt, nb, lane, acc);

    __shared__ __align__(16) float selfF[4][2][64];
    __shared__ __align__(16) float meanF[4][2][64];
    #pragma unroll
    for (int i = 0; i < 2; ++i) {
        selfF[wv][i][lane] = bf16u(xb[((nb + i) << 6) + lane]);
        if (lane < 8) {
            *(float4*)&meanF[wv][i][lane * 8] =
                make_float4(acc[i][0], acc[i][1], acc[i][2], acc[i][3]);
            *(float4*)&meanF[wv][i][lane * 8 + 4] =
                make_float4(acc[i][4], acc[i][5], acc[i][6], acc[i][7]);
        }
    }
    WAVE_LDS_FENCE();

    float ao[2];
    float bb = b1[lane];
    #pragma unroll
    for (int i = 0; i < 2; ++i) ao[i] = bb;
    #pragma unroll
    for (int k = 0; k < IN_CH; ++k) {
        float w = W1[k * 64 + lane];           // lanes coalesced, reused x2
        #pragma unroll
        for (int i = 0; i < 2; ++i) ao[i] = fmaf(selfF[wv][i][k], w, ao[i]);
    }
    #pragma unroll
    for (int k = 0; k < IN_CH; ++k) {
        float w = W1[(IN_CH + k) * 64 + lane];
        #pragma unroll
        for (int i = 0; i < 2; ++i) ao[i] = fmaf(meanF[wv][i][k], w, ao[i]);
    }
    #pragma unroll
    for (int i = 0; i < 2; ++i) {
        float r = fmaxf(ao[i], 0.f);
        __hip_bfloat16 hb = __float2bfloat16(r);
        h1b[((nb + i) << 6) + lane] = *(unsigned short*)&hb;
    }
}

// ---- 3b. W2 pre-transform v2 (R5-verified numerics): 4 nodes/wave, all 64
//      lanes active. lane<32: ys ch j (self+bias, fp32); lane>=32: ym ch j
//      (mean side, bf16). h-rows staged once in LDS (free broadcasts);
//      W2 from global (16KB, L1-hot).
__global__ __launch_bounds__(256) void transform_w2(
    const unsigned short* __restrict__ h1b,
    const float* __restrict__ W2, const float* __restrict__ b2,
    unsigned short* __restrict__ y2b, float* __restrict__ yselff) {
    __shared__ __align__(16) float hrowF[4][4][64];    // 16KB: [wave][node][ch]
    int t    = threadIdx.x;
    int wv   = t >> 6;
    int lane = t & 63;
    int nb4  = blockIdx.x * 16 + wv * 4;               // grid*16 == N_NODES

    // stage 4 rows: lane l -> node l>>4, dwords (l&15) = channels 4q..4q+3
    {
        int in = lane >> 4, q = lane & 15;
        uint2 hv = *(const uint2*)(h1b + (nb4 + in) * 64 + q * 4);
        float4 f;
        f.x = __uint_as_float(hv.x << 16);
        f.y = __uint_as_float(hv.x & 0xffff0000u);
        f.z = __uint_as_float(hv.y << 16);
        f.w = __uint_as_float(hv.y & 0xffff0000u);
        *(float4*)&hrowF[wv][in][q * 4] = f;
    }
    WAVE_LDS_FENCE();

    int jj  = lane & 31;
    int sel = lane >> 5;                               // 0: self (ys), 1: mean (ym)
    const float* Wp = W2 + sel * 64 * 32 + jj;
    float a[4] = {0.f, 0.f, 0.f, 0.f};
    #pragma unroll
    for (int k = 0; k < 64; ++k) {
        float w = Wp[k * 32];                          // 2 coalesced rows / wave
        #pragma unroll
        for (int i = 0; i < 4; ++i)
            a[i] = fmaf(hrowF[wv][i][k], w, a[i]);     // LDS broadcast
    }
    if (sel == 0) {
        float bb = b2[jj];
        #pragma unroll
        for (int i = 0; i < 4; ++i)
            yselff[(nb4 + i) * 32 + jj] = a[i] + bb;
    } else {
        #pragma unroll
        for (int i = 0; i < 4; ++i) {
            __hip_bfloat16 hb = __float2bfloat16(a[i]);
            y2b[(nb4 + i) * 32 + jj] = *(unsigned short*)&hb;
        }
    }
}

// ---- 4. layers 2+3 (R3/R4-proven slim): gather y2b (32ch bf16, 64B/edge,
//      32 neighbors per round trip), mean, add yself, ReLU, dot W3.
__global__ __launch_bounds__(256, 8) void layer23_fused(
    const unsigned short* __restrict__ y2b,
    const int* __restrict__ csr_src, const int* __restrict__ row_start,
    const int* __restrict__ cnt, const float* __restrict__ yselff,
    const float* __restrict__ W3, const float* __restrict__ b3,
    float* __restrict__ out) {
    int wv   = threadIdx.x >> 6;
    int lane = threadIdx.x & 63;
    int nb   = (blockIdx.x * 4 + wv) * 2;
    int g  = lane >> 2;                        // 16 groups of 4 lanes
    int cw = (lane & 3) * 8;                   // bf16 offset within 32-ch row

    int start[2], deg[2], sv[2];
    float acc[2][8];
    #pragma unroll
    for (int i = 0; i < 2; ++i) {
        start[i] = row_start[nb + i];
        deg[i]   = cnt[nb + i];
        #pragma unroll
        for (int c = 0; c < 8; ++c) acc[i][c] = 0.f;
    }
    int dmax = max(deg[0], deg[1]);
    #pragma unroll
    for (int i = 0; i < 2; ++i)
        sv[i] = (lane < deg[i]) ? csr_src[start[i] + lane] : 0;

    #pragma unroll
    for (int cb = 0; cb < 64; cb += 32) {      // 32 neighbors per round trip
        if (cb >= dmax) break;                 // wave-uniform
        int s00 = __shfl(sv[0], cb + g);
        int s01 = __shfl(sv[0], cb + 16 + g);
        int s10 = __shfl(sv[1], cb + g);
        int s11 = __shfl(sv[1], cb + 16 + g);
        uint4 v00 = *(const uint4*)(y2b + s00 * 32 + cw);
        uint4 v01 = *(const uint4*)(y2b + s01 * 32 + cw);
        uint4 v10 = *(const uint4*)(y2b + s10 * 32 + cw);
        uint4 v11 = *(const uint4*)(y2b + s11 * 32 + cw);
        int rem0 = deg[0] - cb;
        int rem1 = deg[1] - cb;
        upadd8(acc[0], v00, (g < rem0) ? 1.f : 0.f);
        upadd8(acc[0], v01, (g + 16 < rem0) ? 1.f : 0.f);
        upadd8(acc[1], v10, (g < rem1) ? 1.f : 0.f);
        upadd8(acc[1], v11, (g + 16 < rem1) ? 1.f : 0.f);
    }
    if (dmax > 64) {                           // rare tail
        for (int i = 0; i < 2; ++i) {
            for (int c0 = 64; c0 < deg[i]; c0 += 64) {
                int rem = deg[i] - c0; if (rem > 64) rem = 64;
                int sx = (lane < rem) ? csr_src[start[i] + c0 + lane] : 0;
                for (int cb = 0; cb < rem; cb += 32) {
                    int s0 = __shfl(sx, cb + g);
                    int s1 = __shfl(sx, cb + 16 + g);
                    float p0 = (cb + g < rem) ? 1.f : 0.f;
                    float p1 = (cb + 16 + g < rem) ? 1.f : 0.f;
                    uint4 v0 = *(const uint4*)(y2b + s0 * 32 + cw);
                    uint4 v1 = *(const uint4*)(y2b + s1 * 32 + cw);
                    upadd8(acc[i], v0, p0);
                    upadd8(acc[i], v1, p1);
                }
            }
        }
    }

    // reduce across the 16 groups (lane bits 2..5), apply mean
    __shared__ __align__(16) float aggF[4][2][32];
    #pragma unroll
    for (int i = 0; i < 2; ++i) {
        float inv = 1.0f / fmaxf((float)deg[i], 1.0f);
        #pragma unroll
        for (int c = 0; c < 8; ++c) {
            float t = acc[i][c];
            t += __shfl_xor(t, 4);
            t += __shfl_xor(t, 8);
            t += __shfl_xor(t, 16);
            t += __shfl_xor(t, 32);
            acc[i][c] = t * inv;
        }
    }
    if (lane < 4) {
        #pragma unroll
        for (int i = 0; i < 2; ++i) {
            *(float4*)&aggF[wv][i][lane * 8] =
                make_float4(acc[i][0], acc[i][1], acc[i][2], acc[i][3]);
            *(float4*)&aggF[wv][i][lane * 8 + 4] =
                make_float4(acc[i][4], acc[i][5], acc[i][6], acc[i][7]);
        }
    }
    WAVE_LDS_FENCE();

    int hh = lane >> 5;                        // half-wave id: node nb+hh
    int j  = lane & 31;
    float pre = yselff[(nb + hh) * 32 + j] + aggF[wv][hh][j];
    float v0 = fmaxf(pre, 0.f) * W3[j];
    #pragma unroll
    for (int off = 1; off <= 16; off <<= 1)
        v0 += __shfl_xor(v0, off);
    if (j == 0)
        out[nb + hh] = v0 + b3[0];
}

extern "C" void kernel_launch(void* const* d_in, const int* in_sizes, int n_in,
                              void* d_out, int out_size, void* d_ws, size_t ws_size,
                              hipStream_t stream) {
    const float* x   = (const float*)d_in[0];
    const int*   ei  = (const int*)d_in[1];
    const int*   src = ei;
    const int*   dst = ei + N_EDGES;
    const float* W1  = (const float*)d_in[2];
    const float* b1  = (const float*)d_in[3];
    const float* W2  = (const float*)d_in[4];
    const float* b2  = (const float*)d_in[5];
    const float* W3  = (const float*)d_in[6];
    const float* b3  = (const float*)d_in[7];
    float* out = (float*)d_out;

    // ws (~78 MB): cursor_rel[512] | cnt | row_start | binned 12.8MB | csr_src 12.8MB |
    //   xb bf16 12.8MB | h1b bf16 12.8MB | y2b bf16 6.4MB | yselff fp32 12.8MB
    char* ws = (char*)d_ws;
    auto align = [](size_t v) { return (v + 255) & ~(size_t)255; };
    size_t o = 0;
    int* cursor_rel = (int*)(ws + o); o = align(o + 512 * 4);
    int* cnt       = (int*)(ws + o); o = align(o + (size_t)N_NODES * 4);
    int* row_start = (int*)(ws + o); o = align(o + (size_t)N_NODES * 4);
    unsigned* binned = (unsigned*)(ws + o); o = align(o + ((size_t)NB << CAPLOG) * 4);
    int* csr_src   = (int*)(ws + o); o = align(o + ((size_t)NB << CAPLOG) * 4);
    unsigned short* xb  = (unsigned short*)(ws + o); o = align(o + (size_t)N_NODES * 64 * 2);
    unsigned short* h1b = (unsigned short*)(ws + o); o = align(o + (size_t)N_NODES * 64 * 2);
    unsigned short* y2b = (unsigned short*)(ws + o); o = align(o + (size_t)N_NODES * 32 * 2);
    float* yselff = (float*)(ws + o); o = align(o + (size_t)N_NODES * 32 * 4);

    (void)hipMemsetAsync(cursor_rel, 0, 512 * sizeof(int), stream);

    bin_pad_kernel<<<NBLK_A + PAD_BLOCKS, 1024, 0, stream>>>(src, dst, cursor_rel,
                                                             binned, x, xb);
    bucket_fine<<<NB, 1024, 0, stream>>>(binned, cursor_rel, cnt, row_start, csr_src);

    layer1_fused<<<N_NODES / 8, 256, 0, stream>>>(xb, csr_src, row_start, cnt,
                                                  W1, b1, h1b);
    transform_w2<<<N_NODES / 16, 256, 0, stream>>>(h1b, W2, b2, y2b, yselff);
    layer23_fused<<<N_NODES / 8, 256, 0, stream>>>(y2b, csr_src, row_start, cnt,
                                                   yselff, W3, b3, out);
}

// Round 8
// 232.812 us; speedup vs baseline: 1.6117x; 1.0241x over previous
//
#include <hip/hip_runtime.h>
#include <hip/hip_bf16.h>

#define N_NODES 100000
#define N_EDGES 1600000
#define IN_CH 50
#define NPB 256                                   // nodes per bucket (dst >> 8)
#define NB ((N_NODES + NPB - 1) / NPB)            // 391 buckets
#define CAPLOG 13                                 // 8192 slots/bucket (max ~4.4K used)
#define EPB 4096
#define NBLK_A ((N_EDGES + EPB - 1) / EPB)        // 391 bin blocks
#define PAD_BLOCKS ((N_NODES * 64) / 1024)        // 6250 pad blocks (1024 thr)

// ---- 1. bin edges into fixed-capacity buckets (+ extra blocks: pad x->xb bf16) ----
// R7/R8: single global pass — payload+bucket staged in LDS during the count pass,
// then scattered from LDS (was: re-read dst+src from global). 27KB LDS.
__global__ __launch_bounds__(1024) void bin_pad_kernel(
    const int* __restrict__ src, const int* __restrict__ dst,
    int* __restrict__ cursor_rel, unsigned* __restrict__ binned,
    const float* __restrict__ x, unsigned short* __restrict__ xb) {
    if (blockIdx.x >= NBLK_A) {                    // pad lane
        int t = (blockIdx.x - NBLK_A) * 1024 + threadIdx.x;  // < N_NODES*64
        int n = t >> 6, c = t & 63;
        float v = (c < IN_CH) ? x[n * IN_CH + c] : 0.0f;
        __hip_bfloat16 hb = __float2bfloat16(v);
        xb[t] = *(unsigned short*)&hb;
        return;
    }
    __shared__ unsigned payl[EPB];                 // 16KB
    __shared__ unsigned short bktl[EPB];           // 8KB
    __shared__ int bc[NB];
    __shared__ int boff[NB];
    int t = threadIdx.x;
    if (t < NB) bc[t] = 0;
    __syncthreads();
    int e0 = blockIdx.x * EPB;
    int ne = min(e0 + EPB, N_EDGES) - e0;
    for (int i = t; i < ne; i += 1024) {
        int d = dst[e0 + i];
        int s = src[e0 + i];
        payl[i] = ((unsigned)(d & 255) << 17) | (unsigned)s;
        bktl[i] = (unsigned short)(d >> 8);
        atomicAdd(&bc[d >> 8], 1);
    }
    __syncthreads();
    if (t < NB) {
        int v = bc[t];
        int rel = v ? atomicAdd(&cursor_rel[t], v) : 0;
        boff[t] = (t << CAPLOG) + rel;
        bc[t] = 0;                                 // reuse as local cursor
    }
    __syncthreads();
    for (int i = t; i < ne; i += 1024) {
        int b = bktl[i];
        int k = atomicAdd(&bc[b], 1);
        binned[boff[b] + k] = payl[i];
    }
}

// ---- 2. per-bucket fine sort -> cnt, row_start, csr_src ----
// R8 (LDS-legal rework of R7): count pass reads binned from global; scatter pass
// re-reads binned (own 32KB slab, L2-hot) into srt LDS; csr_src written fully
// coalesced. 35KB LDS (R7's 67KB pay+srt exceeded the 64KB static limit).
__global__ __launch_bounds__(1024) void bucket_fine(
    const unsigned* __restrict__ binned, const int* __restrict__ cursor_rel,
    int* __restrict__ cnt, int* __restrict__ row_start, int* __restrict__ csr_src) {
    __shared__ unsigned srt[1 << CAPLOG];          // 32KB
    __shared__ int lcnt[NPB];
    __shared__ int lofs[NPB];
    __shared__ int sc[NPB];
    int t = threadIdx.x;
    int b = blockIdx.x;
    int nbase = b * NPB;
    int bbase = b << CAPLOG;
    int ecnt  = cursor_rel[b];
    if (t < NPB) lcnt[t] = 0;
    __syncthreads();
    for (int i = t; i < ecnt; i += 1024)
        atomicAdd(&lcnt[(binned[bbase + i] >> 17) & 255], 1);
    __syncthreads();
    int v = (t < NPB) ? lcnt[t] : 0;
    if (t < NPB) sc[t] = v;
    __syncthreads();
    for (int off = 1; off < NPB; off <<= 1) {      // Hillis-Steele over 256
        int tmp = (t < NPB && t >= off) ? sc[t - off] : 0;
        __syncthreads();
        if (t < NPB) sc[t] += tmp;
        __syncthreads();
    }
    if (t < NPB) {
        int excl = sc[t] - v;
        lofs[t] = excl;
        int n = nbase + t;
        if (n < N_NODES) { cnt[n] = v; row_start[n] = bbase + excl; }
    }
    __syncthreads();
    for (int i = t; i < ecnt; i += 1024) {         // L2-hot re-read
        unsigned p = binned[bbase + i];
        int d = (int)((p >> 17) & 255);
        int k = atomicAdd(&lofs[d], 1);
        srt[k] = p & 0x1FFFFu;
    }
    __syncthreads();
    for (int i = t; i < ecnt; i += 1024)
        csr_src[bbase + i] = (int)srt[i];          // coalesced
}

// unpack 8 bf16 from uint4, predicated fma into acc[0..8)
__device__ __forceinline__ void upadd8(float* a, uint4 v, float p) {
    a[0] = fmaf(p, __uint_as_float(v.x << 16), a[0]);
    a[1] = fmaf(p, __uint_as_float(v.x & 0xffff0000u), a[1]);
    a[2] = fmaf(p, __uint_as_float(v.y << 16), a[2]);
    a[3] = fmaf(p, __uint_as_float(v.y & 0xffff0000u), a[3]);
    a[4] = fmaf(p, __uint_as_float(v.z << 16), a[4]);
    a[5] = fmaf(p, __uint_as_float(v.z & 0xffff0000u), a[5]);
    a[6] = fmaf(p, __uint_as_float(v.w << 16), a[6]);
    a[7] = fmaf(p, __uint_as_float(v.w & 0xffff0000u), a[7]);
}

// wave-local LDS fence: LDS ops of one wave complete in order; no block barrier.
#define WAVE_LDS_FENCE() __asm__ volatile("s_waitcnt lgkmcnt(0)" ::: "memory")

// Gather-mean of 2 nodes per wave over 64-ch bf16 rows (R2-proven shape).
__device__ __forceinline__ void gather2(
    const unsigned short* __restrict__ featb, const int* __restrict__ csr_src,
    const int* __restrict__ row_start, const int* __restrict__ cnt,
    int nb, int lane, float acc[2][8]) {
    int g  = lane >> 3;
    int cw = (lane & 7) * 8;
    int start[2], deg[2], sv[2];
    #pragma unroll
    for (int i = 0; i < 2; ++i) {
        start[i] = row_start[nb + i];
        deg[i]   = cnt[nb + i];
        #pragma unroll
        for (int c = 0; c < 8; ++c) acc[i][c] = 0.f;
    }
    int dmax = max(deg[0], deg[1]);
    #pragma unroll
    for (int i = 0; i < 2; ++i)
        sv[i] = (lane < deg[i]) ? csr_src[start[i] + lane] : 0;

    #pragma unroll
    for (int cb = 0; cb < 64; cb += 16) {
        if (cb >= dmax) break;                 // wave-uniform
        int s00 = __shfl(sv[0], cb + g);
        int s01 = __shfl(sv[0], cb + 8 + g);
        int s10 = __shfl(sv[1], cb + g);
        int s11 = __shfl(sv[1], cb + 8 + g);
        uint4 v00 = *(const uint4*)(featb + s00 * 64 + cw);
        uint4 v01 = *(const uint4*)(featb + s01 * 64 + cw);
        uint4 v10 = *(const uint4*)(featb + s10 * 64 + cw);
        uint4 v11 = *(const uint4*)(featb + s11 * 64 + cw);
        int rem0 = deg[0] - cb;
        int rem1 = deg[1] - cb;
        upadd8(acc[0], v00, (g < rem0) ? 1.f : 0.f);
        upadd8(acc[0], v01, (g + 8 < rem0) ? 1.f : 0.f);
        upadd8(acc[1], v10, (g < rem1) ? 1.f : 0.f);
        upadd8(acc[1], v11, (g + 8 < rem1) ? 1.f : 0.f);
    }
    if (dmax > 64) {                           // rare tail (Poisson(16): ~never)
        for (int i = 0; i < 2; ++i) {
            for (int c0 = 64; c0 < deg[i]; c0 += 64) {
                int rem = deg[i] - c0; if (rem > 64) rem = 64;
                int sx = (lane < rem) ? csr_src[start[i] + c0 + lane] : 0;
                for (int cb = 0; cb < rem; cb += 16) {
                    int s0 = __shfl(sx, cb + g);
                    int s1 = __shfl(sx, cb + 8 + g);
                    float p0 = (cb + g < rem) ? 1.f : 0.f;
                    float p1 = (cb + 8 + g < rem) ? 1.f : 0.f;
                    uint4 v0 = *(const uint4*)(featb + s0 * 64 + cw);
                    uint4 v1 = *(const uint4*)(featb + s1 * 64 + cw);
                    upadd8(acc[i], v0, p0);
                    upadd8(acc[i], v1, p1);
                }
            }
        }
    }
    #pragma unroll
    for (int i = 0; i < 2; ++i) {
        float inv = 1.0f / fmaxf((float)deg[i], 1.0f);
        #pragma unroll
        for (int c = 0; c < 8; ++c) {
            float t = acc[i][c];
            t += __shfl_xor(t, 8);
            t += __shfl_xor(t, 16);
            t += __shfl_xor(t, 32);
            acc[i][c] = t * inv;
        }
    }
}

__device__ __forceinline__ float bf16u(unsigned short u) {
    return __uint_as_float(((unsigned)u) << 16);
}

// ---- 3. layer 1 (R2/R4-proven): 2 nodes/wave; gather(xb) + W1 GEMM -> h1b ----
__global__ __launch_bounds__(256, 8) void layer1_fused(
    const unsigned short* __restrict__ xb,
    const int* __restrict__ csr_src, const int* __restrict__ row_start,
    const int* __restrict__ cnt, const float* __restrict__ W1,
    const float* __restrict__ b1, unsigned short* __restrict__ h1b) {
    int wv   = threadIdx.x >> 6;
    int lane = threadIdx.x & 63;
    int nb   = (blockIdx.x * 4 + wv) * 2;      // N_NODES % 8 == 0

    float acc[2][8];
    gather2(xb, csr_src, row_start, cnt, nb, lane, acc);

    __shared__ __align__(16) float selfF[4][2][64];
    __shared__ __align__(16) float meanF[4][2][64];
    #pragma unroll
    for (int i = 0; i < 2; ++i) {
        selfF[wv][i][lane] = bf16u(xb[((nb + i) << 6) + lane]);
        if (lane < 8) {
            *(float4*)&meanF[wv][i][lane * 8] =
                make_float4(acc[i][0], acc[i][1], acc[i][2], acc[i][3]);
            *(float4*)&meanF[wv][i][lane * 8 + 4] =
                make_float4(acc[i][4], acc[i][5], acc[i][6], acc[i][7]);
        }
    }
    WAVE_LDS_FENCE();

    float ao[2];
    float bb = b1[lane];
    #pragma unroll
    for (int i = 0; i < 2; ++i) ao[i] = bb;
    #pragma unroll
    for (int k = 0; k < IN_CH; ++k) {
        float w = W1[k * 64 + lane];           // lanes coalesced, reused x2
        #pragma unroll
        for (int i = 0; i < 2; ++i) ao[i] = fmaf(selfF[wv][i][k], w, ao[i]);
    }
    #pragma unroll
    for (int k = 0; k < IN_CH; ++k) {
        float w = W1[(IN_CH + k) * 64 + lane];
        #pragma unroll
        for (int i = 0; i < 2; ++i) ao[i] = fmaf(meanF[wv][i][k], w, ao[i]);
    }
    #pragma unroll
    for (int i = 0; i < 2; ++i) {
        float r = fmaxf(ao[i], 0.f);
        __hip_bfloat16 hb = __float2bfloat16(r);
        h1b[((nb + i) << 6) + lane] = *(unsigned short*)&hb;
    }
}

// ---- 3b. W2 pre-transform v2 (R5/R6-proven): 4 nodes/wave, all 64 lanes.
__global__ __launch_bounds__(256) void transform_w2(
    const unsigned short* __restrict__ h1b,
    const float* __restrict__ W2, const float* __restrict__ b2,
    unsigned short* __restrict__ y2b, float* __restrict__ yselff) {
    __shared__ __align__(16) float hrowF[4][4][64];    // 16KB: [wave][node][ch]
    int t    = threadIdx.x;
    int wv   = t >> 6;
    int lane = t & 63;
    int nb4  = blockIdx.x * 16 + wv * 4;               // grid*16 == N_NODES

    {
        int in = lane >> 4, q = lane & 15;
        uint2 hv = *(const uint2*)(h1b + (nb4 + in) * 64 + q * 4);
        float4 f;
        f.x = __uint_as_float(hv.x << 16);
        f.y = __uint_as_float(hv.x & 0xffff0000u);
        f.z = __uint_as_float(hv.y << 16);
        f.w = __uint_as_float(hv.y & 0xffff0000u);
        *(float4*)&hrowF[wv][in][q * 4] = f;
    }
    WAVE_LDS_FENCE();

    int jj  = lane & 31;
    int sel = lane >> 5;                               // 0: self (ys), 1: mean (ym)
    const float* Wp = W2 + sel * 64 * 32 + jj;
    float a[4] = {0.f, 0.f, 0.f, 0.f};
    #pragma unroll
    for (int k = 0; k < 64; ++k) {
        float w = Wp[k * 32];                          // 2 coalesced rows / wave
        #pragma unroll
        for (int i = 0; i < 4; ++i)
            a[i] = fmaf(hrowF[wv][i][k], w, a[i]);     // LDS broadcast
    }
    if (sel == 0) {
        float bb = b2[jj];
        #pragma unroll
        for (int i = 0; i < 4; ++i)
            yselff[(nb4 + i) * 32 + jj] = a[i] + bb;
    } else {
        #pragma unroll
        for (int i = 0; i < 4; ++i) {
            __hip_bfloat16 hb = __float2bfloat16(a[i]);
            y2b[(nb4 + i) * 32 + jj] = *(unsigned short*)&hb;
        }
    }
}

// ---- 4. layers 2+3 (R3/R6-proven slim): gather y2b, mean, +yself, ReLU, dot W3.
__global__ __launch_bounds__(256, 8) void layer23_fused(
    const unsigned short* __restrict__ y2b,
    const int* __restrict__ csr_src, const int* __restrict__ row_start,
    const int* __restrict__ cnt, const float* __restrict__ yselff,
    const float* __restrict__ W3, const float* __restrict__ b3,
    float* __restrict__ out) {
    int wv   = threadIdx.x >> 6;
    int lane = threadIdx.x & 63;
    int nb   = (blockIdx.x * 4 + wv) * 2;
    int g  = lane >> 2;                        // 16 groups of 4 lanes
    int cw = (lane & 3) * 8;                   // bf16 offset within 32-ch row

    int start[2], deg[2], sv[2];
    float acc[2][8];
    #pragma unroll
    for (int i = 0; i < 2; ++i) {
        start[i] = row_start[nb + i];
        deg[i]   = cnt[nb + i];
        #pragma unroll
        for (int c = 0; c < 8; ++c) acc[i][c] = 0.f;
    }
    int dmax = max(deg[0], deg[1]);
    #pragma unroll
    for (int i = 0; i < 2; ++i)
        sv[i] = (lane < deg[i]) ? csr_src[start[i] + lane] : 0;

    #pragma unroll
    for (int cb = 0; cb < 64; cb += 32) {      // 32 neighbors per round trip
        if (cb >= dmax) break;                 // wave-uniform
        int s00 = __shfl(sv[0], cb + g);
        int s01 = __shfl(sv[0], cb + 16 + g);
        int s10 = __shfl(sv[1], cb + g);
        int s11 = __shfl(sv[1], cb + 16 + g);
        uint4 v00 = *(const uint4*)(y2b + s00 * 32 + cw);
        uint4 v01 = *(const uint4*)(y2b + s01 * 32 + cw);
        uint4 v10 = *(const uint4*)(y2b + s10 * 32 + cw);
        uint4 v11 = *(const uint4*)(y2b + s11 * 32 + cw);
        int rem0 = deg[0] - cb;
        int rem1 = deg[1] - cb;
        upadd8(acc[0], v00, (g < rem0) ? 1.f : 0.f);
        upadd8(acc[0], v01, (g + 16 < rem0) ? 1.f : 0.f);
        upadd8(acc[1], v10, (g < rem1) ? 1.f : 0.f);
        upadd8(acc[1], v11, (g + 16 < rem1) ? 1.f : 0.f);
    }
    if (dmax > 64) {                           // rare tail
        for (int i = 0; i < 2; ++i) {
            for (int c0 = 64; c0 < deg[i]; c0 += 64) {
                int rem = deg[i] - c0; if (rem > 64) rem = 64;
                int sx = (lane < rem) ? csr_src[start[i] + c0 + lane] : 0;
                for (int cb = 0; cb < rem; cb += 32) {
                    int s0 = __shfl(sx, cb + g);
                    int s1 = __shfl(sx, cb + 16 + g);
                    float p0 = (cb + g < rem) ? 1.f : 0.f;
                    float p1 = (cb + 16 + g < rem) ? 1.f : 0.f;
                    uint4 v0 = *(const uint4*)(y2b + s0 * 32 + cw);
                    uint4 v1 = *(const uint4*)(y2b + s1 * 32 + cw);
                    upadd8(acc[i], v0, p0);
                    upadd8(acc[i], v1, p1);
                }
            }
        }
    }

    // reduce across the 16 groups (lane bits 2..5), apply mean
    __shared__ __align__(16) float aggF[4][2][32];
    #pragma unroll
    for (int i = 0; i < 2; ++i) {
        float inv = 1.0f / fmaxf((float)deg[i], 1.0f);
        #pragma unroll
        for (int c = 0; c < 8; ++c) {
            float t = acc[i][c];
            t += __shfl_xor(t, 4);
            t += __shfl_xor(t, 8);
            t += __shfl_xor(t, 16);
            t += __shfl_xor(t, 32);
            acc[i][c] = t * inv;
        }
    }
    if (lane < 4) {
        #pragma unroll
        for (int i = 0; i < 2; ++i) {
            *(float4*)&aggF[wv][i][lane * 8] =
                make_float4(acc[i][0], acc[i][1], acc[i][2], acc[i][3]);
            *(float4*)&aggF[wv][i][lane * 8 + 4] =
                make_float4(acc[i][4], acc[i][5], acc[i][6], acc[i][7]);
        }
    }
    WAVE_LDS_FENCE();

    int hh = lane >> 5;                        // half-wave id: node nb+hh
    int j  = lane & 31;
    float pre = yselff[(nb + hh) * 32 + j] + aggF[wv][hh][j];
    float v0 = fmaxf(pre, 0.f) * W3[j];
    #pragma unroll
    for (int off = 1; off <= 16; off <<= 1)
        v0 += __shfl_xor(v0, off);
    if (j == 0)
        out[nb + hh] = v0 + b3[0];
}

extern "C" void kernel_launch(void* const* d_in, const int* in_sizes, int n_in,
                              void* d_out, int out_size, void* d_ws, size_t ws_size,
                              hipStream_t stream) {
    const float* x   = (const float*)d_in[0];
    const int*   ei  = (const int*)d_in[1];
    const int*   src = ei;
    const int*   dst = ei + N_EDGES;
    const float* W1  = (const float*)d_in[2];
    const float* b1  = (const float*)d_in[3];
    const float* W2  = (const float*)d_in[4];
    const float* b2  = (const float*)d_in[5];
    const float* W3  = (const float*)d_in[6];
    const float* b3  = (const float*)d_in[7];
    float* out = (float*)d_out;

    // ws (~78 MB): cursor_rel[512] | cnt | row_start | binned 12.8MB | csr_src 12.8MB |
    //   xb bf16 12.8MB | h1b bf16 12.8MB | y2b bf16 6.4MB | yselff fp32 12.8MB
    char* ws = (char*)d_ws;
    auto align = [](size_t v) { return (v + 255) & ~(size_t)255; };
    size_t o = 0;
    int* cursor_rel = (int*)(ws + o); o = align(o + 512 * 4);
    int* cnt       = (int*)(ws + o); o = align(o + (size_t)N_NODES * 4);
    int* row_start = (int*)(ws + o); o = align(o + (size_t)N_NODES * 4);
    unsigned* binned = (unsigned*)(ws + o); o = align(o + ((size_t)NB << CAPLOG) * 4);
    int* csr_src   = (int*)(ws + o); o = align(o + ((size_t)NB << CAPLOG) * 4);
    unsigned short* xb  = (unsigned short*)(ws + o); o = align(o + (size_t)N_NODES * 64 * 2);
    unsigned short* h1b = (unsigned short*)(ws + o); o = align(o + (size_t)N_NODES * 64 * 2);
    unsigned short* y2b = (unsigned short*)(ws + o); o = align(o + (size_t)N_NODES * 32 * 2);
    float* yselff = (float*)(ws + o); o = align(o + (size_t)N_NODES * 32 * 4);

    (void)hipMemsetAsync(cursor_rel, 0, 512 * sizeof(int), stream);

    bin_pad_kernel<<<NBLK_A + PAD_BLOCKS, 1024, 0, stream>>>(src, dst, cursor_rel,
                                                             binned, x, xb);
    bucket_fine<<<NB, 1024, 0, stream>>>(binned, cursor_rel, cnt, row_start, csr_src);

    layer1_fused<<<N_NODES / 8, 256, 0, stream>>>(xb, csr_src, row_start, cnt,
                                                  W1, b1, h1b);
    transform_w2<<<N_NODES / 16, 256, 0, stream>>>(h1b, W2, b2, y2b, yselff);
    layer23_fused<<<N_NODES / 8, 256, 0, stream>>>(y2b, csr_src, row_start, cnt,
                                                   yselff, W3, b3, out);
}

// Round 9
// 222.980 us; speedup vs baseline: 1.6827x; 1.0441x over previous
//
#include <hip/hip_runtime.h>
#include <hip/hip_bf16.h>

#define N_NODES 100000
#define N_EDGES 1600000
#define IN_CH 50
#define NPB 256                                   // nodes per bucket (dst >> 8)
#define NB ((N_NODES + NPB - 1) / NPB)            // 391 buckets
#define CAPLOG 13                                 // 8192 slots/bucket (max ~4.5K used)
#define EPB 8192                                  // edges per bin block (8/thread)
#define NBLK_A ((N_EDGES + EPB - 1) / EPB)        // 196 bin blocks
#define PAD_BLOCKS ((N_NODES * 32) / 1024)        // 3125 pad blocks (2ch/thread)

// ---- 1. bin edges into fixed-capacity buckets (+ extra blocks: pad x->xb bf16) ----
// R9: rank-from-count — the count pass's atomicAdd return value IS the edge's
// slot; payload held in REGISTERS (8/thread); single LDS-atomic round (was 2);
// single global read of dst/src. Pad lane: 2 channels/thread, float2 reads,
// packed-dword writes.
__global__ __launch_bounds__(1024) void bin_pad_kernel(
    const int* __restrict__ src, const int* __restrict__ dst,
    int* __restrict__ cursor_rel, unsigned* __restrict__ binned,
    const float* __restrict__ x, unsigned short* __restrict__ xb) {
    if (blockIdx.x >= NBLK_A) {                    // pad lane
        int t = (blockIdx.x - NBLK_A) * 1024 + threadIdx.x;  // < N_NODES*32
        int n = t >> 5, q = t & 31;                // q = dword (2 channels)
        unsigned u = 0;
        if (q < 25) {                              // 2q,2q+1 < 50
            float2 v = *(const float2*)(x + n * IN_CH + q * 2);
            __hip_bfloat16 lo = __float2bfloat16(v.x);
            __hip_bfloat16 hi = __float2bfloat16(v.y);
            u = ((unsigned)*(unsigned short*)&hi << 16) | *(unsigned short*)&lo;
        }
        ((unsigned*)xb)[t] = u;
        return;
    }
    __shared__ int bc[NB];
    __shared__ int boff[NB];
    int t = threadIdx.x;
    if (t < NB) bc[t] = 0;
    __syncthreads();
    int e0 = blockIdx.x * EPB;
    int ne = min(e0 + EPB, N_EDGES) - e0;
    unsigned payl[8];
    int bkt[8], rnk[8];
    #pragma unroll
    for (int r = 0; r < 8; ++r) {
        int i = t + r * 1024;
        if (i < ne) {
            int d = dst[e0 + i];
            payl[r] = ((unsigned)(d & 255) << 17) | (unsigned)src[e0 + i];
            bkt[r]  = d >> 8;
            rnk[r]  = atomicAdd(&bc[bkt[r]], 1);   // rank within bucket, this block
        }
    }
    __syncthreads();
    if (t < NB) {
        int v = bc[t];
        int rel = v ? atomicAdd(&cursor_rel[t], v) : 0;
        boff[t] = (t << CAPLOG) + rel;
    }
    __syncthreads();
    #pragma unroll
    for (int r = 0; r < 8; ++r) {
        int i = t + r * 1024;
        if (i < ne)
            binned[boff[bkt[r]] + rnk[r]] = payl[r];
    }
}

// ---- 2. per-bucket fine sort -> cnt, row_start, csr_src ----
// R9: single global read of binned into regs (8/thread); rank-from-count gives
// each edge its slot in the count pass; scatter into srt LDS; coalesced csr
// write (R8-proven). 35KB LDS.
__global__ __launch_bounds__(1024) void bucket_fine(
    const unsigned* __restrict__ binned, const int* __restrict__ cursor_rel,
    int* __restrict__ cnt, int* __restrict__ row_start, int* __restrict__ csr_src) {
    __shared__ unsigned srt[1 << CAPLOG];          // 32KB
    __shared__ int lcnt[NPB];
    __shared__ int lofs[NPB];
    __shared__ int sc[NPB];
    int t = threadIdx.x;
    int b = blockIdx.x;
    int nbase = b * NPB;
    int bbase = b << CAPLOG;
    int ecnt  = cursor_rel[b];                     // <= 8192 = 8*1024 capacity
    if (t < NPB) lcnt[t] = 0;
    __syncthreads();
    unsigned pay[8];
    int rnk[8];
    #pragma unroll
    for (int r = 0; r < 8; ++r) {
        int i = t + r * 1024;
        if (i < ecnt) {
            pay[r] = binned[bbase + i];
            rnk[r] = atomicAdd(&lcnt[(pay[r] >> 17) & 255], 1);  // rank within node
        }
    }
    __syncthreads();
    int v = (t < NPB) ? lcnt[t] : 0;
    if (t < NPB) sc[t] = v;
    __syncthreads();
    for (int off = 1; off < NPB; off <<= 1) {      // Hillis-Steele over 256
        int tmp = (t < NPB && t >= off) ? sc[t - off] : 0;
        __syncthreads();
        if (t < NPB) sc[t] += tmp;
        __syncthreads();
    }
    if (t < NPB) {
        int excl = sc[t] - v;
        lofs[t] = excl;
        int n = nbase + t;
        if (n < N_NODES) { cnt[n] = v; row_start[n] = bbase + excl; }
    }
    __syncthreads();
    #pragma unroll
    for (int r = 0; r < 8; ++r) {
        int i = t + r * 1024;
        if (i < ecnt)
            srt[lofs[(pay[r] >> 17) & 255] + rnk[r]] = pay[r] & 0x1FFFFu;
    }
    __syncthreads();
    for (int i = t; i < ecnt; i += 1024)
        csr_src[bbase + i] = (int)srt[i];          // coalesced
}

// unpack 8 bf16 from uint4, predicated fma into acc[0..8)
__device__ __forceinline__ void upadd8(float* a, uint4 v, float p) {
    a[0] = fmaf(p, __uint_as_float(v.x << 16), a[0]);
    a[1] = fmaf(p, __uint_as_float(v.x & 0xffff0000u), a[1]);
    a[2] = fmaf(p, __uint_as_float(v.y << 16), a[2]);
    a[3] = fmaf(p, __uint_as_float(v.y & 0xffff0000u), a[3]);
    a[4] = fmaf(p, __uint_as_float(v.z << 16), a[4]);
    a[5] = fmaf(p, __uint_as_float(v.z & 0xffff0000u), a[5]);
    a[6] = fmaf(p, __uint_as_float(v.w << 16), a[6]);
    a[7] = fmaf(p, __uint_as_float(v.w & 0xffff0000u), a[7]);
}

// wave-local LDS fence: LDS ops of one wave complete in order; no block barrier.
#define WAVE_LDS_FENCE() __asm__ volatile("s_waitcnt lgkmcnt(0)" ::: "memory")

// Gather-mean of 2 nodes per wave over 64-ch bf16 rows (R2-proven shape).
__device__ __forceinline__ void gather2(
    const unsigned short* __restrict__ featb, const int* __restrict__ csr_src,
    const int* __restrict__ row_start, const int* __restrict__ cnt,
    int nb, int lane, float acc[2][8]) {
    int g  = lane >> 3;
    int cw = (lane & 7) * 8;
    int start[2], deg[2], sv[2];
    #pragma unroll
    for (int i = 0; i < 2; ++i) {
        start[i] = row_start[nb + i];
        deg[i]   = cnt[nb + i];
        #pragma unroll
        for (int c = 0; c < 8; ++c) acc[i][c] = 0.f;
    }
    int dmax = max(deg[0], deg[1]);
    #pragma unroll
    for (int i = 0; i < 2; ++i)
        sv[i] = (lane < deg[i]) ? csr_src[start[i] + lane] : 0;

    #pragma unroll
    for (int cb = 0; cb < 64; cb += 16) {
        if (cb >= dmax) break;                 // wave-uniform
        int s00 = __shfl(sv[0], cb + g);
        int s01 = __shfl(sv[0], cb + 8 + g);
        int s10 = __shfl(sv[1], cb + g);
        int s11 = __shfl(sv[1], cb + 8 + g);
        uint4 v00 = *(const uint4*)(featb + s00 * 64 + cw);
        uint4 v01 = *(const uint4*)(featb + s01 * 64 + cw);
        uint4 v10 = *(const uint4*)(featb + s10 * 64 + cw);
        uint4 v11 = *(const uint4*)(featb + s11 * 64 + cw);
        int rem0 = deg[0] - cb;
        int rem1 = deg[1] - cb;
        upadd8(acc[0], v00, (g < rem0) ? 1.f : 0.f);
        upadd8(acc[0], v01, (g + 8 < rem0) ? 1.f : 0.f);
        upadd8(acc[1], v10, (g < rem1) ? 1.f : 0.f);
        upadd8(acc[1], v11, (g + 8 < rem1) ? 1.f : 0.f);
    }
    if (dmax > 64) {                           // rare tail (Poisson(16): ~never)
        for (int i = 0; i < 2; ++i) {
            for (int c0 = 64; c0 < deg[i]; c0 += 64) {
                int rem = deg[i] - c0; if (rem > 64) rem = 64;
                int sx = (lane < rem) ? csr_src[start[i] + c0 + lane] : 0;
                for (int cb = 0; cb < rem; cb += 16) {
                    int s0 = __shfl(sx, cb + g);
                    int s1 = __shfl(sx, cb + 8 + g);
                    float p0 = (cb + g < rem) ? 1.f : 0.f;
                    float p1 = (cb + 8 + g < rem) ? 1.f : 0.f;
                    uint4 v0 = *(const uint4*)(featb + s0 * 64 + cw);
                    uint4 v1 = *(const uint4*)(featb + s1 * 64 + cw);
                    upadd8(acc[i], v0, p0);
                    upadd8(acc[i], v1, p1);
                }
            }
        }
    }
    #pragma unroll
    for (int i = 0; i < 2; ++i) {
        float inv = 1.0f / fmaxf((float)deg[i], 1.0f);
        #pragma unroll
        for (int c = 0; c < 8; ++c) {
            float t = acc[i][c];
            t += __shfl_xor(t, 8);
            t += __shfl_xor(t, 16);
            t += __shfl_xor(t, 32);
            acc[i][c] = t * inv;
        }
    }
}

__device__ __forceinline__ float bf16u(unsigned short u) {
    return __uint_as_float(((unsigned)u) << 16);
}

// ---- 3. layer 1 (R2/R4-proven): 2 nodes/wave; gather(xb) + W1 GEMM -> h1b ----
__global__ __launch_bounds__(256, 8) void layer1_fused(
    const unsigned short* __restrict__ xb,
    const int* __restrict__ csr_src, const int* __restrict__ row_start,
    const int* __restrict__ cnt, const float* __restrict__ W1,
    const float* __restrict__ b1, unsigned short* __restrict__ h1b) {
    int wv   = threadIdx.x >> 6;
    int lane = threadIdx.x & 63;
    int nb   = (blockIdx.x * 4 + wv) * 2;      // N_NODES % 8 == 0

    float acc[2][8];
    gather2(xb, csr_src, row_start, cnt, nb, lane, acc);

    __shared__ __align__(16) float selfF[4][2][64];
    __shared__ __align__(16) float meanF[4][2][64];
    #pragma unroll
    for (int i = 0; i < 2; ++i) {
        selfF[wv][i][lane] = bf16u(xb[((nb + i) << 6) + lane]);
        if (lane < 8) {
            *(float4*)&meanF[wv][i][lane * 8] =
                make_float4(acc[i][0], acc[i][1], acc[i][2], acc[i][3]);
            *(float4*)&meanF[wv][i][lane * 8 + 4] =
                make_float4(acc[i][4], acc[i][5], acc[i][6], acc[i][7]);
        }
    }
    WAVE_LDS_FENCE();

    float ao[2];
    float bb = b1[lane];
    #pragma unroll
    for (int i = 0; i < 2; ++i) ao[i] = bb;
    #pragma unroll
    for (int k = 0; k < IN_CH; ++k) {
        float w = W1[k * 64 + lane];           // lanes coalesced, reused x2
        #pragma unroll
        for (int i = 0; i < 2; ++i) ao[i] = fmaf(selfF[wv][i][k], w, ao[i]);
    }
    #pragma unroll
    for (int k = 0; k < IN_CH; ++k) {
        float w = W1[(IN_CH + k) * 64 + lane];
        #pragma unroll
        for (int i = 0; i < 2; ++i) ao[i] = fmaf(meanF[wv][i][k], w, ao[i]);
    }
    #pragma unroll
    for (int i = 0; i < 2; ++i) {
        float r = fmaxf(ao[i], 0.f);
        __hip_bfloat16 hb = __float2bfloat16(r);
        h1b[((nb + i) << 6) + lane] = *(unsigned short*)&hb;
    }
}

// ---- 3b. W2 pre-transform v2 (R5/R6-proven): 4 nodes/wave, all 64 lanes.
__global__ __launch_bounds__(256) void transform_w2(
    const unsigned short* __restrict__ h1b,
    const float* __restrict__ W2, const float* __restrict__ b2,
    unsigned short* __restrict__ y2b, float* __restrict__ yselff) {
    __shared__ __align__(16) float hrowF[4][4][64];    // 16KB: [wave][node][ch]
    int t    = threadIdx.x;
    int wv   = t >> 6;
    int lane = t & 63;
    int nb4  = blockIdx.x * 16 + wv * 4;               // grid*16 == N_NODES

    {
        int in = lane >> 4, q = lane & 15;
        uint2 hv = *(const uint2*)(h1b + (nb4 + in) * 64 + q * 4);
        float4 f;
        f.x = __uint_as_float(hv.x << 16);
        f.y = __uint_as_float(hv.x & 0xffff0000u);
        f.z = __uint_as_float(hv.y << 16);
        f.w = __uint_as_float(hv.y & 0xffff0000u);
        *(float4*)&hrowF[wv][in][q * 4] = f;
    }
    WAVE_LDS_FENCE();

    int jj  = lane & 31;
    int sel = lane >> 5;                               // 0: self (ys), 1: mean (ym)
    const float* Wp = W2 + sel * 64 * 32 + jj;
    float a[4] = {0.f, 0.f, 0.f, 0.f};
    #pragma unroll
    for (int k = 0; k < 64; ++k) {
        float w = Wp[k * 32];                          // 2 coalesced rows / wave
        #pragma unroll
        for (int i = 0; i < 4; ++i)
            a[i] = fmaf(hrowF[wv][i][k], w, a[i]);     // LDS broadcast
    }
    if (sel == 0) {
        float bb = b2[jj];
        #pragma unroll
        for (int i = 0; i < 4; ++i)
            yselff[(nb4 + i) * 32 + jj] = a[i] + bb;
    } else {
        #pragma unroll
        for (int i = 0; i < 4; ++i) {
            __hip_bfloat16 hb = __float2bfloat16(a[i]);
            y2b[(nb4 + i) * 32 + jj] = *(unsigned short*)&hb;
        }
    }
}

// ---- 4. layers 2+3 (R3/R6-proven slim): gather y2b, mean, +yself, ReLU, dot W3.
__global__ __launch_bounds__(256, 8) void layer23_fused(
    const unsigned short* __restrict__ y2b,
    const int* __restrict__ csr_src, const int* __restrict__ row_start,
    const int* __restrict__ cnt, const float* __restrict__ yselff,
    const float* __restrict__ W3, const float* __restrict__ b3,
    float* __restrict__ out) {
    int wv   = threadIdx.x >> 6;
    int lane = threadIdx.x & 63;
    int nb   = (blockIdx.x * 4 + wv) * 2;
    int g  = lane >> 2;                        // 16 groups of 4 lanes
    int cw = (lane & 3) * 8;                   // bf16 offset within 32-ch row

    int start[2], deg[2], sv[2];
    float acc[2][8];
    #pragma unroll
    for (int i = 0; i < 2; ++i) {
        start[i] = row_start[nb + i];
        deg[i]   = cnt[nb + i];
        #pragma unroll
        for (int c = 0; c < 8; ++c) acc[i][c] = 0.f;
    }
    int dmax = max(deg[0], deg[1]);
    #pragma unroll
    for (int i = 0; i < 2; ++i)
        sv[i] = (lane < deg[i]) ? csr_src[start[i] + lane] : 0;

    #pragma unroll
    for (int cb = 0; cb < 64; cb += 32) {      // 32 neighbors per round trip
        if (cb >= dmax) break;                 // wave-uniform
        int s00 = __shfl(sv[0], cb + g);
        int s01 = __shfl(sv[0], cb + 16 + g);
        int s10 = __shfl(sv[1], cb + g);
        int s11 = __shfl(sv[1], cb + 16 + g);
        uint4 v00 = *(const uint4*)(y2b + s00 * 32 + cw);
        uint4 v01 = *(const uint4*)(y2b + s01 * 32 + cw);
        uint4 v10 = *(const uint4*)(y2b + s10 * 32 + cw);
        uint4 v11 = *(const uint4*)(y2b + s11 * 32 + cw);
        int rem0 = deg[0] - cb;
        int rem1 = deg[1] - cb;
        upadd8(acc[0], v00, (g < rem0) ? 1.f : 0.f);
        upadd8(acc[0], v01, (g + 16 < rem0) ? 1.f : 0.f);
        upadd8(acc[1], v10, (g < rem1) ? 1.f : 0.f);
        upadd8(acc[1], v11, (g + 16 < rem1) ? 1.f : 0.f);
    }
    if (dmax > 64) {                           // rare tail
        for (int i = 0; i < 2; ++i) {
            for (int c0 = 64; c0 < deg[i]; c0 += 64) {
                int rem = deg[i] - c0; if (rem > 64) rem = 64;
                int sx = (lane < rem) ? csr_src[start[i] + c0 + lane] : 0;
                for (int cb = 0; cb < rem; cb += 32) {
                    int s0 = __shfl(sx, cb + g);
                    int s1 = __shfl(sx, cb + 16 + g);
                    float p0 = (cb + g < rem) ? 1.f : 0.f;
                    float p1 = (cb + 16 + g < rem) ? 1.f : 0.f;
                    uint4 v0 = *(const uint4*)(y2b + s0 * 32 + cw);
                    uint4 v1 = *(const uint4*)(y2b + s1 * 32 + cw);
                    upadd8(acc[i], v0, p0);
                    upadd8(acc[i], v1, p1);
                }
            }
        }
    }

    // reduce across the 16 groups (lane bits 2..5), apply mean
    __shared__ __align__(16) float aggF[4][2][32];
    #pragma unroll
    for (int i = 0; i < 2; ++i) {
        float inv = 1.0f / fmaxf((float)deg[i], 1.0f);
        #pragma unroll
        for (int c = 0; c < 8; ++c) {
            float t = acc[i][c];
            t += __shfl_xor(t, 4);
            t += __shfl_xor(t, 8);
            t += __shfl_xor(t, 16);
            t += __shfl_xor(t, 32);
            acc[i][c] = t * inv;
        }
    }
    if (lane < 4) {
        #pragma unroll
        for (int i = 0; i < 2; ++i) {
            *(float4*)&aggF[wv][i][lane * 8] =
                make_float4(acc[i][0], acc[i][1], acc[i][2], acc[i][3]);
            *(float4*)&aggF[wv][i][lane * 8 + 4] =
                make_float4(acc[i][4], acc[i][5], acc[i][6], acc[i][7]);
        }
    }
    WAVE_LDS_FENCE();

    int hh = lane >> 5;                        // half-wave id: node nb+hh
    int j  = lane & 31;
    float pre = yselff[(nb + hh) * 32 + j] + aggF[wv][hh][j];
    float v0 = fmaxf(pre, 0.f) * W3[j];
    #pragma unroll
    for (int off = 1; off <= 16; off <<= 1)
        v0 += __shfl_xor(v0, off);
    if (j == 0)
        out[nb + hh] = v0 + b3[0];
}

extern "C" void kernel_launch(void* const* d_in, const int* in_sizes, int n_in,
                              void* d_out, int out_size, void* d_ws, size_t ws_size,
                              hipStream_t stream) {
    const float* x   = (const float*)d_in[0];
    const int*   ei  = (const int*)d_in[1];
    const int*   src = ei;
    const int*   dst = ei + N_EDGES;
    const float* W1  = (const float*)d_in[2];
    const float* b1  = (const float*)d_in[3];
    const float* W2  = (const float*)d_in[4];
    const float* b2  = (const float*)d_in[5];
    const float* W3  = (const float*)d_in[6];
    const float* b3  = (const float*)d_in[7];
    float* out = (float*)d_out;

    // ws (~78 MB): cursor_rel[512] | cnt | row_start | binned 12.8MB | csr_src 12.8MB |
    //   xb bf16 12.8MB | h1b bf16 12.8MB | y2b bf16 6.4MB | yselff fp32 12.8MB
    char* ws = (char*)d_ws;
    auto align = [](size_t v) { return (v + 255) & ~(size_t)255; };
    size_t o = 0;
    int* cursor_rel = (int*)(ws + o); o = align(o + 512 * 4);
    int* cnt       = (int*)(ws + o); o = align(o + (size_t)N_NODES * 4);
    int* row_start = (int*)(ws + o); o = align(o + (size_t)N_NODES * 4);
    unsigned* binned = (unsigned*)(ws + o); o = align(o + ((size_t)NB << CAPLOG) * 4);
    int* csr_src   = (int*)(ws + o); o = align(o + ((size_t)NB << CAPLOG) * 4);
    unsigned short* xb  = (unsigned short*)(ws + o); o = align(o + (size_t)N_NODES * 64 * 2);
    unsigned short* h1b = (unsigned short*)(ws + o); o = align(o + (size_t)N_NODES * 64 * 2);
    unsigned short* y2b = (unsigned short*)(ws + o); o = align(o + (size_t)N_NODES * 32 * 2);
    float* yselff = (float*)(ws + o); o = align(o + (size_t)N_NODES * 32 * 4);

    (void)hipMemsetAsync(cursor_rel, 0, 512 * sizeof(int), stream);

    bin_pad_kernel<<<NBLK_A + PAD_BLOCKS, 1024, 0, stream>>>(src, dst, cursor_rel,
                                                             binned, x, xb);
    bucket_fine<<<NB, 1024, 0, stream>>>(binned, cursor_rel, cnt, row_start, csr_src);

    layer1_fused<<<N_NODES / 8, 256, 0, stream>>>(xb, csr_src, row_start, cnt,
                                                  W1, b1, h1b);
    transform_w2<<<N_NODES / 16, 256, 0, stream>>>(h1b, W2, b2, y2b, yselff);
    layer23_fused<<<N_NODES / 8, 256, 0, stream>>>(y2b, csr_src, row_start, cnt,
                                                   yselff, W3, b3, out);
}